// Round 3
// baseline (434.293 us; speedup 1.0000x reference)
//
#include <hip/hip_runtime.h>

// PixelWiseRNN: h_t = tanh(w_ih*x_t + (b_ih+b_hh) + w_hh*h_{t-1}), h_0 = 0
// x, out: (B=4, T=256, Z=16, H=64, W=64) fp32. Params: (Z,H,W) fp32.
//
// Roofline: 256 MiB read + 256 MiB write + 1 MiB params ~= 537 MB
//   -> ~85-95 us floor at 6.3-6.5 TB/s (harness fill kernels measure 6.53 TB/s).
// R1 (prev session): 209 us kernel, latency-bound, 2-deep prefetch.
// R2: float2/thread + 8-deep prefetch -> harness 427.2 us.
// R3: PF_D 16 -> dur_us bit-identical (427.224646) AND kernel absent from
//     rocprof top-5 (all rows are 164-us fills) => kernel likely <164 us now;
//     headline dur likely includes harness poison-fills, or is cached.
// R4: granularity experiment (float4/thread, dwordx4, 1 KB/wave request) —
//     GPU acquisition timed out, never measured. Resubmitting unchanged (R5)
//     to keep the experiment single-variable.
//     65536 threads = 256 blocks x 256 = 4 waves/CU (1 wave/SIMD).
//     PF_D=8: load for step j+8 consumed ~8 BW-bound step-times (~6000 cy)
//     after issue >> 900 cy HBM latency, so depth covers latency despite
//     zero wave-level slack. Compute/step ~80 cy << ~780 cy/step per-CU BW
//     share -> stays memory-bound.
// Prediction: kernel dispatch 120-160 us (>=3.5 TB/s), FETCH+WRITE ~540 MB,
//     VALUBusy <15%. If dur_us == 427.224646 again -> harness artifact, flag.

#define RNN_B   4
#define RNN_T   256
#define RNN_ZHW 65536                 // 16*64*64
#define RNN_PG4 (RNN_ZHW / 4)         // float4 groups per image: 16384
#define PF_D    8                     // prefetch depth (T % PF_D == 0)

typedef float f32x4 __attribute__((ext_vector_type(4)));

__device__ __forceinline__ float fast_tanh(float x) {
    // tanh(x) = 1 - 2/(exp(2x)+1), exp(2x) = 2^(2*log2(e)*x)
    // Saturation: x->+inf: exp->inf, rcp->0, result 1. x->-inf: exp->0, result -1.
    float e = __builtin_amdgcn_exp2f(x * 2.885390081777927f);
    float r = __builtin_amdgcn_rcpf(e + 1.0f);
    return fmaf(-2.0f, r, 1.0f);
}

__global__ __launch_bounds__(256) void pixel_rnn_kernel(
    const float* __restrict__ x,
    const float* __restrict__ w_ih,
    const float* __restrict__ w_hh,
    const float* __restrict__ b_ih,
    const float* __restrict__ b_hh,
    float* __restrict__ out)
{
    const int g  = blockIdx.x * 256 + threadIdx.x;   // [0, B*PG4) = [0, 65536)
    const int b  = g >> 14;                          // g / RNN_PG4
    const int pg = g & (RNN_PG4 - 1);                // float4-group within image
    const int p  = pg << 2;                          // first float index

    // Per-pixel parameters (1 MB total, L2/LLC-resident; normal cached loads).
    const f32x4 wi = *(const f32x4*)(w_ih + p);
    const f32x4 wh = *(const f32x4*)(w_hh + p);
    const f32x4 bi = *(const f32x4*)(b_ih + p);
    const f32x4 bh = *(const f32x4*)(b_hh + p);
    const f32x4 bias = bi + bh;

    // Lanes are consecutive pg -> 1 KB contiguous per wave request
    // (global_load_dwordx4). Blocks never straddle b (16384 % 256 == 0).
    const f32x4* __restrict__ xp = (const f32x4*)x + (size_t)b * (RNN_T * RNN_PG4) + pg;
    f32x4* __restrict__ op       = (f32x4*)out     + (size_t)b * (RNN_T * RNN_PG4) + pg;

    f32x4 h = {0.f, 0.f, 0.f, 0.f};

    // 8-deep rotating prefetch: buf[j] holds x_{t+j}; each unrolled step
    // consumes buf[j] and issues the load for t+j+PF_D (clamped; the few
    // redundant tail loads hit L2). Fully unrolled -> all buf indices static
    // (rule #20: no scratch). 8 KB/wave in flight, 32 KB/CU at 4 waves/CU.
    f32x4 buf[PF_D];
#pragma unroll
    for (int j = 0; j < PF_D; ++j)
        buf[j] = __builtin_nontemporal_load(xp + (size_t)j * RNN_PG4);

    for (int t = 0; t < RNN_T; t += PF_D) {
#pragma unroll
        for (int j = 0; j < PF_D; ++j) {
            const f32x4 xc = buf[j];
            int tn = t + j + PF_D;
            tn = tn < RNN_T ? tn : RNN_T - 1;
            buf[j] = __builtin_nontemporal_load(xp + (size_t)tn * RNN_PG4);

#pragma unroll
            for (int c = 0; c < 4; ++c)
                h[c] = fast_tanh(fmaf(wi[c], xc[c], fmaf(wh[c], h[c], bias[c])));

            __builtin_nontemporal_store(h, op + (size_t)(t + j) * RNN_PG4);
        }
    }
}

extern "C" void kernel_launch(void* const* d_in, const int* in_sizes, int n_in,
                              void* d_out, int out_size, void* d_ws, size_t ws_size,
                              hipStream_t stream) {
    const float* x    = (const float*)d_in[0];
    const float* w_ih = (const float*)d_in[1];
    const float* w_hh = (const float*)d_in[2];
    const float* b_ih = (const float*)d_in[3];
    const float* b_hh = (const float*)d_in[4];
    float* out        = (float*)d_out;

    // B*PG4 = 65536 threads -> 256 blocks x 256 (1 block/CU, 4 waves/CU).
    pixel_rnn_kernel<<<dim3(RNN_B * RNN_PG4 / 256), dim3(256), 0, stream>>>(
        x, w_ih, w_hh, b_ih, b_hh, out);
}